// Round 4
// baseline (210.569 us; speedup 1.0000x reference)
//
#include <hip/hip_runtime.h>
#include <math.h>

#define ALPHA 0.2f

// Padded strides: odd multiples of 64B lines to kill L1 set-aliasing
#define XS   544    // xbf / hamT row stride in shorts (17 lines)
#define HS   4128   // hBT col stride in shorts (129 lines)
#define HCS  66048  // 16 cols * HS

typedef __attribute__((ext_vector_type(8))) short short8;
typedef __attribute__((ext_vector_type(4))) float f32x4;
typedef __attribute__((ext_vector_type(4))) int i32x4;

__device__ __forceinline__ unsigned short f2bf(float f) {
    unsigned int x = __float_as_uint(f);
    x += 0x7fffu + ((x >> 16) & 1u);   // RNE
    return (unsigned short)(x >> 16);
}
__device__ __forceinline__ unsigned int pack_rne(float lo, float hi) {
    return (unsigned int)f2bf(lo) | ((unsigned int)f2bf(hi) << 16);
}
// truncating bf16 pack (bias cancels in w/L since L sums the same truncated w)
__device__ __forceinline__ unsigned int pack_trunc(float lo, float hi) {
    return __builtin_amdgcn_perm(__float_as_uint(hi), __float_as_uint(lo), 0x07060302u);
}
// bit j of x -> 0x0 / 0xFFFFFFFF
__device__ __forceinline__ unsigned int bitmask1(unsigned int x, int j) {
    return (unsigned int)(((int)(x << (31 - j))) >> 31);
}

// ---------------------------------------------------------------------------
// K0 (fused prep): [0,1024): x fp32->bf16 (padded rows). [1024,1152):
// hamilton transposed bf16. [1152,3200): adj -> 1-bit mask, 32/thread.
// ---------------------------------------------------------------------------
__global__ __launch_bounds__(256) void k_prep(const float* __restrict__ x,
                                              const float* __restrict__ W,
                                              const int* __restrict__ adj,
                                              unsigned short* __restrict__ xbf,
                                              unsigned short* __restrict__ hamT,
                                              unsigned int* __restrict__ adjp32) {
    const int b = blockIdx.x;
    if (b < 1024) {                       // ---- x convert: 2M elems, 8/thread
        const int gid = b * 256 + threadIdx.x;
        const int row = gid >> 6, c8 = (gid & 63) * 8;
        const float4* xp = (const float4*)x + (size_t)gid * 2;
        const float4 f0 = xp[0], f1 = xp[1];
        const uint4 o = {pack_rne(f0.x, f0.y), pack_rne(f0.z, f0.w),
                         pack_rne(f1.x, f1.y), pack_rne(f1.z, f1.w)};
        *(uint4*)(xbf + (size_t)row * XS + c8) = o;
    } else if (b < 1152) {                // ---- hamilton: sign mask 0x5390
        const int gid = (b - 1024) * 256 + threadIdx.x;    // 32768
        const int head = gid >> 13;
        const int rem  = gid & 8191;
        const int o = rem >> 6, f8 = rem & 63;
        const int ob = o >> 5, oc = o & 31;
        float v[8];
#pragma unroll
        for (int j = 0; j < 8; j++) {
            const int f = f8 * 8 + j;
            const int bq = f >> 7, f0 = f & 127;
            const float s = ((0x5390u >> ((bq << 2) | ob)) & 1u) ? -1.0f : 1.0f;
            v[j] = s * W[(head << 14) + (f0 << 7) + (((bq ^ ob) << 5) | oc)];
        }
        const uint4 pk = {pack_rne(v[0], v[1]), pack_rne(v[2], v[3]),
                          pack_rne(v[4], v[5]), pack_rne(v[6], v[7])};
        *(uint4*)(hamT + (size_t)(head * 128 + o) * XS + f8 * 8) = pk;
    } else {                              // ---- adj bit-pack: 64 MB -> 2 MB
        const int gid = (b - 1152) * 256 + threadIdx.x;    // 0..524287
        const int4* ap = (const int4*)(adj + (size_t)gid * 32);
        unsigned int u = 0;
#pragma unroll
        for (int q = 0; q < 8; q++) {
            const int4 v = ap[q];
            u |= (v.x > 0 ? 1u : 0u) << (q * 4);
            u |= (v.y > 0 ? 2u : 0u) << (q * 4);
            u |= (v.z > 0 ? 4u : 0u) << (q * 4);
            u |= (v.w > 0 ? 8u : 0u) << (q * 4);
        }
        adjp32[gid] = u;
    }
}

// ---------------------------------------------------------------------------
// K1: h = x @ ham via bf16 MFMA (passed R5/R7/R8). Block: 4 waves x 16 rows,
// 128 cols. Outputs hBT (padded col-major bf16) + fsE/fdE.
// ---------------------------------------------------------------------------
__global__ __launch_bounds__(256) void k_h(const unsigned short* __restrict__ xbf,
                                           const unsigned short* __restrict__ hamT,
                                           const float* __restrict__ a,
                                           unsigned short* __restrict__ hBT,
                                           float2* __restrict__ fsE,
                                           float2* __restrict__ fdE) {
    const int t = threadIdx.x;
    const int head = blockIdx.y;
    const int n0 = blockIdx.x * 64;
    const int wv = t >> 6, lane = t & 63;
    const int quad = lane >> 4, nl = lane & 15;
    const unsigned short* ap = xbf + (size_t)(n0 + wv * 16 + nl) * XS + quad * 8;
    const unsigned short* bp = hamT + (size_t)(head * 128 + nl) * XS + quad * 8;
    f32x4 acc[8];
#pragma unroll
    for (int ct = 0; ct < 8; ct++) acc[ct] = (f32x4){0.f, 0.f, 0.f, 0.f};
    for (int kc = 0; kc < 16; kc++) {
        const short8 af = *(const short8*)(ap + kc * 32);
#pragma unroll
        for (int ct = 0; ct < 8; ct++) {
            const short8 bf_ = *(const short8*)(bp + (size_t)ct * 16 * XS + kc * 32);
            acc[ct] = __builtin_amdgcn_mfma_f32_16x16x32_bf16(af, bf_, acc[ct], 0, 0, 0);
        }
    }
    const int rbase = n0 + wv * 16 + quad * 4;
#pragma unroll
    for (int ct = 0; ct < 8; ct++) {
        const uint2 pk = {pack_rne(acc[ct][0], acc[ct][1]), pack_rne(acc[ct][2], acc[ct][3])};
        *(uint2*)(hBT + (size_t)(head * 128 + ct * 16 + nl) * HS + rbase) = pk;
    }
    float fsr[4] = {0.f, 0.f, 0.f, 0.f}, fdr[4] = {0.f, 0.f, 0.f, 0.f};
#pragma unroll
    for (int ct = 0; ct < 8; ct++) {
        const int col = ct * 16 + nl;
        const float as = a[head * 256 + col];
        const float ad = a[head * 256 + 128 + col];
#pragma unroll
        for (int r = 0; r < 4; r++) {
            fsr[r] += acc[ct][r] * as;
            fdr[r] += acc[ct][r] * ad;
        }
    }
#pragma unroll
    for (int off = 1; off < 16; off <<= 1)
#pragma unroll
        for (int r = 0; r < 4; r++) {
            fsr[r] += __shfl_xor(fsr[r], off, 64);
            fdr[r] += __shfl_xor(fdr[r], off, 64);
        }
    if (nl == 0) {
#pragma unroll
        for (int r = 0; r < 4; r++) {
            const int n = rbase + r;
            fsE[(head << 12) + n] = make_float2(__expf(fsr[r]), __expf(ALPHA * fsr[r]));
            fdE[(head << 12) + n] = make_float2(__expf(fdr[r]), __expf(ALPHA * fdr[r]));
        }
    }
}

// ---------------------------------------------------------------------------
// K2: partial h' = softmax-numerator(mask(leaky(fs+fd))) @ h over an m-HALF.
// R3 post-mortem: 2 waves/SIMD needs VGPR<=256 (pool quantum 512/wave-slot,
// m69), NOT <=128 — round 0's 216-VGPR wave was 2-wave-eligible all along;
// it was GRID-limited (256 blocks = 1/CU). R3's 32-row blocks doubled per-CU
// B-traffic (full panel per block) and halved per-chunk compute -> slower.
// Fix: split M instead. Grid 512 = (head, 64-row tile, m-half of 2048).
// Per-wave shape IDENTICAL to round 0 (rt=4, ct=8, 16 chunks of m=32);
// per-CU B-traffic unchanged (2 x 0.5MB half-panels); 2 blocks/CU = 2
// waves/SIMD. Blocks write unnormalized partials (half 0 -> out buffer,
// half 1 -> pacc1) + per-row partial L; k_comb normalizes+ELU.
// bid&7 -> (head,mhalf): each XCD L2 serves one 0.5MB half-panel.
// 512-thread shapes are banned (R1/R2: backend hard-caps them at 128 VGPR).
// ---------------------------------------------------------------------------
#define WELT(e1, ea, j, bits, es) \
    __uint_as_float(__float_as_uint(fmaxf((es).x * (e1), (es).y * (ea))) & bitmask1((bits), (j)))
#define WPK(f4, jb, bits, es) \
    pack_trunc(WELT((f4).x, (f4).y, (jb), (bits), (es)), \
               WELT((f4).z, (f4).w, (jb) + 1, (bits), (es)))

#define LOADM(S, mcn) do {                                                \
    const int _mo = (mcn) * 32;                                           \
    _Pragma("unroll")                                                     \
    for (int _ct = 0; _ct < 8; _ct++)                                     \
        Bst[S][_ct] = *(const short8*)(bbase + (size_t)_ct * HCS + _mo);  \
    _Pragma("unroll")                                                     \
    for (int _rt = 0; _rt < 4; _rt++) Kst[S][_rt] = ap[_rt][(mcn) * 4];   \
    _Pragma("unroll")                                                     \
    for (int _q = 0; _q < 4; _q++) Fst[S][_q] = fdb[(mcn) * 16 + _q];     \
} while (0)

#define EXECM(S) do {                                                     \
    short8 _af[4];                                                        \
    _Pragma("unroll")                                                     \
    for (int _rt = 0; _rt < 4; _rt++) {                                   \
        const i32x4 _ai = {(int)WPK(Fst[S][0], 0, Kst[S][_rt], es[_rt]),  \
                           (int)WPK(Fst[S][1], 2, Kst[S][_rt], es[_rt]),  \
                           (int)WPK(Fst[S][2], 4, Kst[S][_rt], es[_rt]),  \
                           (int)WPK(Fst[S][3], 6, Kst[S][_rt], es[_rt])}; \
        _af[_rt] = __builtin_bit_cast(short8, _ai);                       \
    }                                                                     \
    _Pragma("unroll")                                                     \
    for (int _rt = 0; _rt < 4; _rt++) {                                   \
        _Pragma("unroll")                                                 \
        for (int _ct = 0; _ct < 8; _ct++)                                 \
            acc[_rt][_ct] = __builtin_amdgcn_mfma_f32_16x16x32_bf16(      \
                _af[_rt], Bst[S][_ct], acc[_rt][_ct], 0, 0, 0);           \
        accL[_rt] = __builtin_amdgcn_mfma_f32_16x16x32_bf16(              \
            _af[_rt], ones, accL[_rt], 0, 0, 0);                          \
    }                                                                     \
} while (0)

__global__ __launch_bounds__(256, 2) void k_attn(const unsigned char* __restrict__ adjp,
                                                 const float2* __restrict__ fsE,
                                                 const float2* __restrict__ fdE,
                                                 const unsigned short* __restrict__ hBT,
                                                 float* __restrict__ out,
                                                 float* __restrict__ pacc1,
                                                 float* __restrict__ pL) {
    __shared__ f32x4 cbuf[1536];   // 24 KB: one rt-round of partials [ct][j][lane]
    __shared__ f32x4 Lbuf[1024];   // 16 KB: [wv*4+rt][lane]
    const int t = threadIdx.x;
    const int head  = blockIdx.x & 3;          // bid&7 -> (head,mhalf) per XCD
    const int mhalf = (blockIdx.x >> 2) & 1;
    const int n0 = (blockIdx.x >> 3) * 64;
    const int wv = t >> 6, lane = t & 63;
    const int quad = lane >> 4, nl = lane & 15;
    const int m0base = mhalf * 2048 + (wv << 9);   // this wave's 512-wide strip
    float2 es[4];
    const unsigned char* ap[4];
#pragma unroll
    for (int rt = 0; rt < 4; rt++) {
        es[rt] = fsE[(head << 12) + n0 + rt * 16 + nl];
        ap[rt] = adjp + ((size_t)(n0 + rt * 16 + nl) << 9) + (m0base >> 3) + quad;
    }
    const float4* fdb = (const float4*)(fdE + (head << 12) + m0base + quad * 8);
    const unsigned short* bbase = hBT + (size_t)(head * 128 + nl) * HS + quad * 8 + m0base;
    const short8 ones = __builtin_bit_cast(short8,
        (i32x4){0x3F803F80, 0x3F803F80, 0x3F803F80, 0x3F803F80});
    f32x4 acc[4][8], accL[4];
#pragma unroll
    for (int rt = 0; rt < 4; rt++) {
        accL[rt] = (f32x4){0.f, 0.f, 0.f, 0.f};
#pragma unroll
        for (int ct = 0; ct < 8; ct++) acc[rt][ct] = (f32x4){0.f, 0.f, 0.f, 0.f};
    }
    short8 Bst[2][8];
    unsigned int Kst[2][4];
    float4 Fst[2][4];
    LOADM(0, 0);
    LOADM(1, 1);
    for (int mc = 0; mc < 16; mc += 2) {       // 16 m-chunks of 32 per wave
        EXECM(0);
        LOADM(0, (mc + 2) & 15);               // wrap load harmless
        EXECM(1);
        LOADM(1, (mc + 3) & 15);
    }
    // ---- combine 4 m-strips, one rt-round at a time; write raw partials ----
    float* const pdst = (mhalf == 0) ? out : pacc1;
#pragma unroll
    for (int rt = 0; rt < 4; rt++) Lbuf[(wv * 4 + rt) * 64 + lane] = accL[rt];
#pragma unroll
    for (int rt = 0; rt < 4; rt++) {
        if (rt > 0) __syncthreads();           // prev round's reads done
#pragma unroll
        for (int ct = 0; ct < 8; ct++) {
            const int owner = ct & 3;
            if (owner != wv) {
                const int j = (wv - owner - 1) & 3;
                cbuf[(ct * 3 + j) * 64 + lane] = acc[rt][ct];
            }
        }
        __syncthreads();                       // also covers Lbuf writes (rt=0)
        if (wv == 0 && nl == 0) {              // block-level partial L per row
            f32x4 Lt = (f32x4){0.f, 0.f, 0.f, 0.f};
#pragma unroll
            for (int v = 0; v < 4; v++) Lt += Lbuf[(v * 4 + rt) * 64 + lane];
#pragma unroll
            for (int r = 0; r < 4; r++)
                pL[mhalf * 16384 + (head << 12) + n0 + rt * 16 + quad * 4 + r] = Lt[r];
        }
#pragma unroll
        for (int ct = 0; ct < 8; ct++) {
            if ((ct & 3) == wv) {              // wave-uniform; ct compile-time
                f32x4 tot = acc[rt][ct];
#pragma unroll
                for (int j = 0; j < 3; j++) tot += cbuf[(ct * 3 + j) * 64 + lane];
#pragma unroll
                for (int r = 0; r < 4; r++)
                    pdst[(size_t)(n0 + rt * 16 + quad * 4 + r) * 512
                         + head * 128 + ct * 16 + nl] = tot[r];
            }
        }
    }
}

// ---------------------------------------------------------------------------
// K3: combine m-halves: out = ELU((t0+t1) / (L0+L1)). 24 MB traffic, ~4 us.
// ---------------------------------------------------------------------------
__global__ __launch_bounds__(256) void k_comb(const float* __restrict__ pacc1,
                                              const float* __restrict__ pL,
                                              float* __restrict__ out) {
    const int gid = blockIdx.x * 256 + threadIdx.x;     // 524288 threads
    const int c4 = gid & 127, row = gid >> 7;
    const int head = c4 >> 5;
    const size_t base = (size_t)row * 512 + c4 * 4;
    const float4 t0 = *(const float4*)(out + base);
    const float4 t1 = *(const float4*)(pacc1 + base);
    const float L = pL[(head << 12) + row] + pL[16384 + (head << 12) + row];
    const float iL = (L > 0.f) ? (1.0f / L) : 0.0f;
    float4 o;
    float v;
    v = (t0.x + t1.x) * iL; o.x = v > 0.f ? v : (__expf(v) - 1.0f);
    v = (t0.y + t1.y) * iL; o.y = v > 0.f ? v : (__expf(v) - 1.0f);
    v = (t0.z + t1.z) * iL; o.z = v > 0.f ? v : (__expf(v) - 1.0f);
    v = (t0.w + t1.w) * iL; o.w = v > 0.f ? v : (__expf(v) - 1.0f);
    *(float4*)(out + base) = o;
}

extern "C" void kernel_launch(void* const* d_in, const int* in_sizes, int n_in,
                              void* d_out, int out_size, void* d_ws, size_t ws_size,
                              hipStream_t stream) {
    (void)in_sizes; (void)n_in; (void)out_size; (void)ws_size;
    const float* x   = (const float*)d_in[0];   // (4096,512) fp32
    const int*   adj = (const int*)d_in[1];     // (4096,4096) i32
    const float* W   = (const float*)d_in[2];   // (4,128,128) fp32
    const float* a   = (const float*)d_in[3];   // (4,256) fp32
    float* out = (float*)d_out;                 // (4096,512) fp32

    // ws layout (k_attn-live regions first; xbf/hamT die after k_h and are
    // overlaid by pacc1, so total ws = 14.5 MB):
    char* ws = (char*)d_ws;
    unsigned short* hBT  = (unsigned short*)(ws);             // 4*128*4128*2 = 4227072
    unsigned char*  adjp = (unsigned char*)(ws + 4227072);    // 2 MB bitmask -> ends 6324224
    float2*         fsE  = (float2*)(ws + 6324224);           // 128 KB -> ends 6455296
    float2*         fdE  = (float2*)(ws + 6455296);           // 128 KB -> ends 6586368
    float*          pL   = (float*)(ws + 6586368);            // 2*4*4096*4 = 128 KB -> 6717440
    unsigned short* xbf  = (unsigned short*)(ws + 6717440);   // 4456448 -> ends 11173888
    unsigned short* hamT = (unsigned short*)(ws + 11173888);  // 557056 -> ends 11730944
    float*          pacc1 = (float*)(ws + 6717440);           // 8 MB, overlays xbf/hamT

    hipLaunchKernelGGL(k_prep, dim3(3200),    dim3(256), 0, stream,
                       x, W, adj, xbf, hamT, (unsigned int*)adjp);
    hipLaunchKernelGGL(k_h,    dim3(64, 4),   dim3(256), 0, stream, xbf, hamT, a, hBT, fsE, fdE);
    hipLaunchKernelGGL(k_attn, dim3(512),     dim3(256), 0, stream,
                       adjp, fsE, fdE, hBT, out, pacc1, pL);
    hipLaunchKernelGGL(k_comb, dim3(2048),    dim3(256), 0, stream, pacc1, pL, out);
}

// Round 5
// 168.679 us; speedup vs baseline: 1.2483x; 1.2483x over previous
//
#include <hip/hip_runtime.h>
#include <math.h>

#define ALPHA 0.2f

// Padded strides: odd multiples of 64B lines to kill L1 set-aliasing
#define XS   544    // xbf / hamT row stride in shorts (17 lines)
#define HS   4128   // hBT col stride in shorts (129 lines)
#define HCS  66048  // 16 cols * HS

typedef __attribute__((ext_vector_type(8))) short short8;
typedef __attribute__((ext_vector_type(4))) float f32x4;
typedef __attribute__((ext_vector_type(4))) int i32x4;

__device__ __forceinline__ unsigned short f2bf(float f) {
    unsigned int x = __float_as_uint(f);
    x += 0x7fffu + ((x >> 16) & 1u);   // RNE
    return (unsigned short)(x >> 16);
}
__device__ __forceinline__ unsigned int pack_rne(float lo, float hi) {
    return (unsigned int)f2bf(lo) | ((unsigned int)f2bf(hi) << 16);
}
// truncating bf16 pack (bias cancels in w/L since L sums the same truncated w)
__device__ __forceinline__ unsigned int pack_trunc(float lo, float hi) {
    return __builtin_amdgcn_perm(__float_as_uint(hi), __float_as_uint(lo), 0x07060302u);
}
// bit j of x -> 0x0 / 0xFFFFFFFF
__device__ __forceinline__ unsigned int bitmask1(unsigned int x, int j) {
    return (unsigned int)(((int)(x << (31 - j))) >> 31);
}

// ---------------------------------------------------------------------------
// K0 (fused prep): [0,1024): x fp32->bf16 (padded rows). [1024,1152):
// hamilton transposed bf16. [1152,3200): adj -> 1-bit mask, 32/thread.
// ---------------------------------------------------------------------------
__global__ __launch_bounds__(256) void k_prep(const float* __restrict__ x,
                                              const float* __restrict__ W,
                                              const int* __restrict__ adj,
                                              unsigned short* __restrict__ xbf,
                                              unsigned short* __restrict__ hamT,
                                              unsigned int* __restrict__ adjp32) {
    const int b = blockIdx.x;
    if (b < 1024) {                       // ---- x convert: 2M elems, 8/thread
        const int gid = b * 256 + threadIdx.x;
        const int row = gid >> 6, c8 = (gid & 63) * 8;
        const float4* xp = (const float4*)x + (size_t)gid * 2;
        const float4 f0 = xp[0], f1 = xp[1];
        const uint4 o = {pack_rne(f0.x, f0.y), pack_rne(f0.z, f0.w),
                         pack_rne(f1.x, f1.y), pack_rne(f1.z, f1.w)};
        *(uint4*)(xbf + (size_t)row * XS + c8) = o;
    } else if (b < 1152) {                // ---- hamilton: sign mask 0x5390
        const int gid = (b - 1024) * 256 + threadIdx.x;    // 32768
        const int head = gid >> 13;
        const int rem  = gid & 8191;
        const int o = rem >> 6, f8 = rem & 63;
        const int ob = o >> 5, oc = o & 31;
        float v[8];
#pragma unroll
        for (int j = 0; j < 8; j++) {
            const int f = f8 * 8 + j;
            const int bq = f >> 7, f0 = f & 127;
            const float s = ((0x5390u >> ((bq << 2) | ob)) & 1u) ? -1.0f : 1.0f;
            v[j] = s * W[(head << 14) + (f0 << 7) + (((bq ^ ob) << 5) | oc)];
        }
        const uint4 pk = {pack_rne(v[0], v[1]), pack_rne(v[2], v[3]),
                          pack_rne(v[4], v[5]), pack_rne(v[6], v[7])};
        *(uint4*)(hamT + (size_t)(head * 128 + o) * XS + f8 * 8) = pk;
    } else {                              // ---- adj bit-pack: 64 MB -> 2 MB
        const int gid = (b - 1152) * 256 + threadIdx.x;    // 0..524287
        const int4* ap = (const int4*)(adj + (size_t)gid * 32);
        unsigned int u = 0;
#pragma unroll
        for (int q = 0; q < 8; q++) {
            const int4 v = ap[q];
            u |= (v.x > 0 ? 1u : 0u) << (q * 4);
            u |= (v.y > 0 ? 2u : 0u) << (q * 4);
            u |= (v.z > 0 ? 4u : 0u) << (q * 4);
            u |= (v.w > 0 ? 8u : 0u) << (q * 4);
        }
        adjp32[gid] = u;
    }
}

// ---------------------------------------------------------------------------
// K1: h = x @ ham via bf16 MFMA (passed R5/R7/R8). Block: 4 waves x 16 rows,
// 128 cols. Outputs hBT (padded col-major bf16) + fsE/fdE.
// ---------------------------------------------------------------------------
__global__ __launch_bounds__(256) void k_h(const unsigned short* __restrict__ xbf,
                                           const unsigned short* __restrict__ hamT,
                                           const float* __restrict__ a,
                                           unsigned short* __restrict__ hBT,
                                           float2* __restrict__ fsE,
                                           float2* __restrict__ fdE) {
    const int t = threadIdx.x;
    const int head = blockIdx.y;
    const int n0 = blockIdx.x * 64;
    const int wv = t >> 6, lane = t & 63;
    const int quad = lane >> 4, nl = lane & 15;
    const unsigned short* ap = xbf + (size_t)(n0 + wv * 16 + nl) * XS + quad * 8;
    const unsigned short* bp = hamT + (size_t)(head * 128 + nl) * XS + quad * 8;
    f32x4 acc[8];
#pragma unroll
    for (int ct = 0; ct < 8; ct++) acc[ct] = (f32x4){0.f, 0.f, 0.f, 0.f};
    for (int kc = 0; kc < 16; kc++) {
        const short8 af = *(const short8*)(ap + kc * 32);
#pragma unroll
        for (int ct = 0; ct < 8; ct++) {
            const short8 bf_ = *(const short8*)(bp + (size_t)ct * 16 * XS + kc * 32);
            acc[ct] = __builtin_amdgcn_mfma_f32_16x16x32_bf16(af, bf_, acc[ct], 0, 0, 0);
        }
    }
    const int rbase = n0 + wv * 16 + quad * 4;
#pragma unroll
    for (int ct = 0; ct < 8; ct++) {
        const uint2 pk = {pack_rne(acc[ct][0], acc[ct][1]), pack_rne(acc[ct][2], acc[ct][3])};
        *(uint2*)(hBT + (size_t)(head * 128 + ct * 16 + nl) * HS + rbase) = pk;
    }
    float fsr[4] = {0.f, 0.f, 0.f, 0.f}, fdr[4] = {0.f, 0.f, 0.f, 0.f};
#pragma unroll
    for (int ct = 0; ct < 8; ct++) {
        const int col = ct * 16 + nl;
        const float as = a[head * 256 + col];
        const float ad = a[head * 256 + 128 + col];
#pragma unroll
        for (int r = 0; r < 4; r++) {
            fsr[r] += acc[ct][r] * as;
            fdr[r] += acc[ct][r] * ad;
        }
    }
#pragma unroll
    for (int off = 1; off < 16; off <<= 1)
#pragma unroll
        for (int r = 0; r < 4; r++) {
            fsr[r] += __shfl_xor(fsr[r], off, 64);
            fdr[r] += __shfl_xor(fdr[r], off, 64);
        }
    if (nl == 0) {
#pragma unroll
        for (int r = 0; r < 4; r++) {
            const int n = rbase + r;
            fsE[(head << 12) + n] = make_float2(__expf(fsr[r]), __expf(ALPHA * fsr[r]));
            fdE[(head << 12) + n] = make_float2(__expf(fdr[r]), __expf(ALPHA * fdr[r]));
        }
    }
}

// ---------------------------------------------------------------------------
// K2: partial h' = softmax-numerator(mask(leaky(fs+fd))) @ h over an m-HALF.
// Grid 512 = (head, 64-row tile, m-half of 2048); per-wave shape identical to
// the proven round-0 kernel (rt=4, ct=8, 16 m-chunks of 32). Per-CU B-traffic
// unchanged (2 x 0.5MB half-panels/CU); 2 blocks/CU = 2 waves/SIMD.
// LAUNCH-BOUNDS LAW (R1/R2/R4 measured): ANY second arg >= 2 makes the
// backend budget 4 waves/EU -> hard 128-VGPR cap -> acc spills (WRITE_SIZE
// 130-171 MB, k_attn 89-99 us). Plain (256) compiles this wave at ~216 VGPR
// (round 0 evidence) -> <=256 so hardware co-resides 2 blocks/CU on its own
// (LDS 40KB x 2 = 80 <= 160KB). Do NOT re-add the second arg.
// Blocks write unnormalized partials (half 0 -> out, half 1 -> pacc1) +
// per-row partial L; k_comb normalizes+ELU. bid&7 -> (head,mhalf) per XCD.
// ---------------------------------------------------------------------------
#define WELT(e1, ea, j, bits, es) \
    __uint_as_float(__float_as_uint(fmaxf((es).x * (e1), (es).y * (ea))) & bitmask1((bits), (j)))
#define WPK(f4, jb, bits, es) \
    pack_trunc(WELT((f4).x, (f4).y, (jb), (bits), (es)), \
               WELT((f4).z, (f4).w, (jb) + 1, (bits), (es)))

#define LOADM(S, mcn) do {                                                \
    const int _mo = (mcn) * 32;                                           \
    _Pragma("unroll")                                                     \
    for (int _ct = 0; _ct < 8; _ct++)                                     \
        Bst[S][_ct] = *(const short8*)(bbase + (size_t)_ct * HCS + _mo);  \
    _Pragma("unroll")                                                     \
    for (int _rt = 0; _rt < 4; _rt++) Kst[S][_rt] = ap[_rt][(mcn) * 4];   \
    _Pragma("unroll")                                                     \
    for (int _q = 0; _q < 4; _q++) Fst[S][_q] = fdb[(mcn) * 16 + _q];     \
} while (0)

#define EXECM(S) do {                                                     \
    short8 _af[4];                                                        \
    _Pragma("unroll")                                                     \
    for (int _rt = 0; _rt < 4; _rt++) {                                   \
        const i32x4 _ai = {(int)WPK(Fst[S][0], 0, Kst[S][_rt], es[_rt]),  \
                           (int)WPK(Fst[S][1], 2, Kst[S][_rt], es[_rt]),  \
                           (int)WPK(Fst[S][2], 4, Kst[S][_rt], es[_rt]),  \
                           (int)WPK(Fst[S][3], 6, Kst[S][_rt], es[_rt])}; \
        _af[_rt] = __builtin_bit_cast(short8, _ai);                       \
    }                                                                     \
    _Pragma("unroll")                                                     \
    for (int _rt = 0; _rt < 4; _rt++) {                                   \
        _Pragma("unroll")                                                 \
        for (int _ct = 0; _ct < 8; _ct++)                                 \
            acc[_rt][_ct] = __builtin_amdgcn_mfma_f32_16x16x32_bf16(      \
                _af[_rt], Bst[S][_ct], acc[_rt][_ct], 0, 0, 0);           \
        accL[_rt] = __builtin_amdgcn_mfma_f32_16x16x32_bf16(              \
            _af[_rt], ones, accL[_rt], 0, 0, 0);                          \
    }                                                                     \
} while (0)

__global__ __launch_bounds__(256) void k_attn(const unsigned char* __restrict__ adjp,
                                              const float2* __restrict__ fsE,
                                              const float2* __restrict__ fdE,
                                              const unsigned short* __restrict__ hBT,
                                              float* __restrict__ out,
                                              float* __restrict__ pacc1,
                                              float* __restrict__ pL) {
    __shared__ f32x4 cbuf[1536];   // 24 KB: one rt-round of partials [ct][j][lane]
    __shared__ f32x4 Lbuf[1024];   // 16 KB: [wv*4+rt][lane]
    const int t = threadIdx.x;
    const int head  = blockIdx.x & 3;          // bid&7 -> (head,mhalf) per XCD
    const int mhalf = (blockIdx.x >> 2) & 1;
    const int n0 = (blockIdx.x >> 3) * 64;
    const int wv = t >> 6, lane = t & 63;
    const int quad = lane >> 4, nl = lane & 15;
    const int m0base = mhalf * 2048 + (wv << 9);   // this wave's 512-wide strip
    float2 es[4];
    const unsigned char* ap[4];
#pragma unroll
    for (int rt = 0; rt < 4; rt++) {
        es[rt] = fsE[(head << 12) + n0 + rt * 16 + nl];
        ap[rt] = adjp + ((size_t)(n0 + rt * 16 + nl) << 9) + (m0base >> 3) + quad;
    }
    const float4* fdb = (const float4*)(fdE + (head << 12) + m0base + quad * 8);
    const unsigned short* bbase = hBT + (size_t)(head * 128 + nl) * HS + quad * 8 + m0base;
    const short8 ones = __builtin_bit_cast(short8,
        (i32x4){0x3F803F80, 0x3F803F80, 0x3F803F80, 0x3F803F80});
    f32x4 acc[4][8], accL[4];
#pragma unroll
    for (int rt = 0; rt < 4; rt++) {
        accL[rt] = (f32x4){0.f, 0.f, 0.f, 0.f};
#pragma unroll
        for (int ct = 0; ct < 8; ct++) acc[rt][ct] = (f32x4){0.f, 0.f, 0.f, 0.f};
    }
    short8 Bst[2][8];
    unsigned int Kst[2][4];
    float4 Fst[2][4];
    LOADM(0, 0);
    LOADM(1, 1);
    for (int mc = 0; mc < 16; mc += 2) {       // 16 m-chunks of 32 per wave
        EXECM(0);
        LOADM(0, (mc + 2) & 15);               // wrap load harmless
        EXECM(1);
        LOADM(1, (mc + 3) & 15);
    }
    // ---- combine 4 m-strips, one rt-round at a time; write raw partials ----
    float* const pdst = (mhalf == 0) ? out : pacc1;
#pragma unroll
    for (int rt = 0; rt < 4; rt++) Lbuf[(wv * 4 + rt) * 64 + lane] = accL[rt];
#pragma unroll
    for (int rt = 0; rt < 4; rt++) {
        if (rt > 0) __syncthreads();           // prev round's reads done
#pragma unroll
        for (int ct = 0; ct < 8; ct++) {
            const int owner = ct & 3;
            if (owner != wv) {
                const int j = (wv - owner - 1) & 3;
                cbuf[(ct * 3 + j) * 64 + lane] = acc[rt][ct];
            }
        }
        __syncthreads();                       // also covers Lbuf writes (rt=0)
        if (wv == 0 && nl == 0) {              // block-level partial L per row
            f32x4 Lt = (f32x4){0.f, 0.f, 0.f, 0.f};
#pragma unroll
            for (int v = 0; v < 4; v++) Lt += Lbuf[(v * 4 + rt) * 64 + lane];
#pragma unroll
            for (int r = 0; r < 4; r++)
                pL[mhalf * 16384 + (head << 12) + n0 + rt * 16 + quad * 4 + r] = Lt[r];
        }
#pragma unroll
        for (int ct = 0; ct < 8; ct++) {
            if ((ct & 3) == wv) {              // wave-uniform; ct compile-time
                f32x4 tot = acc[rt][ct];
#pragma unroll
                for (int j = 0; j < 3; j++) tot += cbuf[(ct * 3 + j) * 64 + lane];
#pragma unroll
                for (int r = 0; r < 4; r++)
                    pdst[(size_t)(n0 + rt * 16 + quad * 4 + r) * 512
                         + head * 128 + ct * 16 + nl] = tot[r];
            }
        }
    }
}

// ---------------------------------------------------------------------------
// K3: combine m-halves: out = ELU((t0+t1) / (L0+L1)). 24 MB traffic, ~4 us.
// ---------------------------------------------------------------------------
__global__ __launch_bounds__(256) void k_comb(const float* __restrict__ pacc1,
                                              const float* __restrict__ pL,
                                              float* __restrict__ out) {
    const int gid = blockIdx.x * 256 + threadIdx.x;     // 524288 threads
    const int c4 = gid & 127, row = gid >> 7;
    const int head = c4 >> 5;
    const size_t base = (size_t)row * 512 + c4 * 4;
    const float4 t0 = *(const float4*)(out + base);
    const float4 t1 = *(const float4*)(pacc1 + base);
    const float L = pL[(head << 12) + row] + pL[16384 + (head << 12) + row];
    const float iL = (L > 0.f) ? (1.0f / L) : 0.0f;
    float4 o;
    float v;
    v = (t0.x + t1.x) * iL; o.x = v > 0.f ? v : (__expf(v) - 1.0f);
    v = (t0.y + t1.y) * iL; o.y = v > 0.f ? v : (__expf(v) - 1.0f);
    v = (t0.z + t1.z) * iL; o.z = v > 0.f ? v : (__expf(v) - 1.0f);
    v = (t0.w + t1.w) * iL; o.w = v > 0.f ? v : (__expf(v) - 1.0f);
    *(float4*)(out + base) = o;
}

extern "C" void kernel_launch(void* const* d_in, const int* in_sizes, int n_in,
                              void* d_out, int out_size, void* d_ws, size_t ws_size,
                              hipStream_t stream) {
    (void)in_sizes; (void)n_in; (void)out_size; (void)ws_size;
    const float* x   = (const float*)d_in[0];   // (4096,512) fp32
    const int*   adj = (const int*)d_in[1];     // (4096,4096) i32
    const float* W   = (const float*)d_in[2];   // (4,128,128) fp32
    const float* a   = (const float*)d_in[3];   // (4,256) fp32
    float* out = (float*)d_out;                 // (4096,512) fp32

    // ws layout (k_attn-live regions first; xbf/hamT die after k_h and are
    // overlaid by pacc1, so total ws = 14.5 MB):
    char* ws = (char*)d_ws;
    unsigned short* hBT  = (unsigned short*)(ws);             // 4*128*4128*2 = 4227072
    unsigned char*  adjp = (unsigned char*)(ws + 4227072);    // 2 MB bitmask -> ends 6324224
    float2*         fsE  = (float2*)(ws + 6324224);           // 128 KB -> ends 6455296
    float2*         fdE  = (float2*)(ws + 6455296);           // 128 KB -> ends 6586368
    float*          pL   = (float*)(ws + 6586368);            // 2*4*4096*4 = 128 KB -> 6717440
    unsigned short* xbf  = (unsigned short*)(ws + 6717440);   // 4456448 -> ends 11173888
    unsigned short* hamT = (unsigned short*)(ws + 11173888);  // 557056 -> ends 11730944
    float*          pacc1 = (float*)(ws + 6717440);           // 8 MB, overlays xbf/hamT

    hipLaunchKernelGGL(k_prep, dim3(3200),    dim3(256), 0, stream,
                       x, W, adj, xbf, hamT, (unsigned int*)adjp);
    hipLaunchKernelGGL(k_h,    dim3(64, 4),   dim3(256), 0, stream, xbf, hamT, a, hBT, fsE, fdE);
    hipLaunchKernelGGL(k_attn, dim3(512),     dim3(256), 0, stream,
                       adjp, fsE, fdE, hBT, out, pacc1, pL);
    hipLaunchKernelGGL(k_comb, dim3(2048),    dim3(256), 0, stream, pacc1, pL, out);
}